// Round 4
// baseline (93.417 us; speedup 1.0000x reference)
//
#include <hip/hip_runtime.h>

#define BS 16
#define SEQL 2048
#define NH 16
#define PD 64
#define ND 16
#define LB 64
#define NC 32          // SEQL / LB
#define NHP (NH * PD)  // 1024
#define NHN (NH * ND)  // 256

typedef __attribute__((ext_vector_type(8))) short bf16x8;
typedef __attribute__((ext_vector_type(4))) float f32x4;

static __device__ __forceinline__ unsigned short f2bf(float x) {
  unsigned int u = __float_as_uint(x);
  return (unsigned short)((u + 0x7FFFu + ((u >> 16) & 1u)) >> 16);  // RNE
}
static __device__ __forceinline__ unsigned int pk2(float a, float b) {
  return (unsigned int)f2bf(a) | ((unsigned int)f2bf(b) << 16);
}
// Barrier that drains LDS ops only: prefetch global->reg loads (no cross-wave
// consumers) stay in flight across it. __syncthreads would drain vmcnt(0).
static __device__ __forceinline__ void barrier_lgkm() {
  asm volatile("s_waitcnt lgkmcnt(0)" ::: "memory");
  __builtin_amdgcn_s_barrier();
  asm volatile("" ::: "memory");
}

// One block per (b,h), 8 waves. Per chunk (2 lgkm-barriers):
//  window A: phase1 M-tiles (10 lower-tri tiles + 2 zero tiles) -> sM;
//            hoist all window-B fragments that don't depend on sM.
//  window B: 16 Y-tiles (2/wave) + 4 S-tiles (waves 4-7, ST ping-pong update)
//            + staging of chunk c+1 into alt buffers + prefetch issue c+2.
__global__ __launch_bounds__(512) void ssd_fused(
    const float* __restrict__ Xg, const float* __restrict__ Ag,
    const float* __restrict__ Bg, const float* __restrict__ Cg,
    float* __restrict__ Yg) {
  const int h = blockIdx.x & (NH - 1);
  const int b = blockIdx.x >> 4;
  const int t = threadIdx.x;
  const int w = t >> 6;
  const int lane = t & 63;
  const int g = lane >> 4;
  const int cc = lane & 15;

  // sXt: stride 64 (128B), XOR-swizzled: 8-elem chunk k stored at k^((p>>3)&7)
  __shared__ __align__(16) unsigned short sXt[2][PD][64];
  __shared__ __align__(16) unsigned short sM[LB][LB + 8];
  __shared__ __align__(16) unsigned short sB[LB][ND + 8];
  __shared__ __align__(16) unsigned short sC[LB][ND + 8];      // C' = e_l * C
  __shared__ __align__(16) unsigned short sBdT[ND][LB + 8];    // (dec*B)^T
  __shared__ __align__(16) float sSTf[2][PD][ND + 4];          // ST fp32 ping-pong
  __shared__ __align__(16) unsigned short sSTb[2][PD][ND + 8]; // ST bf16 mirror

  // thread mappings
  const int xp0 = (t & 15) * 4, xl0 = (t >> 4) * 2;  // X: 4p x 2l block
  const int bl = t >> 3, bn0 = (t & 7) * 2;          // B/C rows
  const int n_bt = t >> 5, l_bt = (t & 31) * 2;      // BdT: 1 n x 2 l

  // phase-1 tile tables (nibble-packed to avoid stack arrays)
  const int lb1 = (int)((0x33222110u >> (4 * w)) & 0xFu);
  const int sb1 = (int)((0x20210100u >> (4 * w)) & 0xFu);

  float4 px0, px1;
  float2 pb2, pc2;
  float pbA_v, pbB_v, pa;
  float er, rr, etot, er_n, rr_n, etot_n;

#define PREF(ci) do { \
    const size_t s0_ = (size_t)(b * SEQL + (ci) * LB); \
    px0 = *(const float4*)&Xg[(s0_ + xl0) * NHP + h * PD + xp0]; \
    px1 = *(const float4*)&Xg[(s0_ + xl0 + 1) * NHP + h * PD + xp0]; \
    pb2 = *(const float2*)&Bg[(s0_ + bl) * NHN + h * ND + bn0]; \
    pc2 = *(const float2*)&Cg[(s0_ + bl) * NHN + h * ND + bn0]; \
    pbA_v = Bg[(s0_ + l_bt) * NHN + h * ND + n_bt]; \
    pbB_v = Bg[(s0_ + l_bt + 1) * NHN + h * ND + n_bt]; \
    pa = Ag[(s0_ + lane) * NH + h]; \
  } while (0)

#define CUMSUM_STAGE(bufi) do { \
    float v_ = pa; \
    _Pragma("unroll") \
    for (int d_ = 1; d_ < 64; d_ <<= 1) { \
      float o_ = __shfl_up(v_, d_, 64); \
      if (lane >= d_) v_ += o_; \
    } \
    er_n = expf(v_); rr_n = expf(-v_); etot_n = __shfl(er_n, 63); \
    _Pragma("unroll") \
    for (int j_ = 0; j_ < 4; ++j_) { \
      const int p_ = xp0 + j_; \
      const int idx_ = (((xl0 >> 3) ^ ((p_ >> 3) & 7)) << 3) | (xl0 & 7); \
      *(unsigned int*)&sXt[bufi][p_][idx_] = pk2((&px0.x)[j_], (&px1.x)[j_]); \
    } \
    { const float el_ = __shfl(er_n, bl); \
      *(unsigned int*)&sB[bl][bn0] = pk2(pb2.x, pb2.y); \
      *(unsigned int*)&sC[bl][bn0] = pk2(el_ * pc2.x, el_ * pc2.y); } \
    { const float d0_ = etot_n * __shfl(rr_n, l_bt); \
      const float d1_ = etot_n * __shfl(rr_n, l_bt + 1); \
      *(unsigned int*)&sBdT[n_bt][l_bt] = pk2(d0_ * pbA_v, d1_ * pbB_v); } \
  } while (0)

  const bf16x8 zf8 = {0, 0, 0, 0, 0, 0, 0, 0};

  auto xfrag = [&](int buf, int p_, int l0_) -> bf16x8 {
    const int idx_ = (((l0_ >> 3) ^ ((p_ >> 3) & 7)) << 3);
    return *(const bf16x8*)&sXt[buf][p_][idx_];
  };

  auto p1tile = [&](int lb_, int sb_) {
    const int l_ = lb_ * 16 + cc;
    bf16x8 cf = zf8, bfr = zf8;
    if (g < 2) {
      cf = *(const bf16x8*)&sC[l_][g * 8];
      bfr = *(const bf16x8*)&sB[sb_ * 16 + cc][g * 8];
    }
    f32x4 z4 = {0.f, 0.f, 0.f, 0.f};
    f32x4 d = __builtin_amdgcn_mfma_f32_16x16x32_bf16(bfr, cf, z4, 0, 0, 0);
    // lane holds D'[s = sb*16+4g+r][l]
    float mm[4];
#pragma unroll
    for (int r = 0; r < 4; ++r) {
      const int srow = sb_ * 16 + 4 * g + r;
      mm[r] = d[r] * __shfl(rr, srow);
      if (sb_ == lb_ && (4 * g + r) > cc) mm[r] = 0.f;
    }
    uint2 o;
    o.x = pk2(mm[0], mm[1]);
    o.y = pk2(mm[2], mm[3]);
    *(uint2*)&sM[l_][sb_ * 16 + g * 4] = o;
  };

  // ---------------- prologue ----------------
  for (int i = t; i < PD * (ND + 4); i += 512) ((float*)sSTf[0])[i] = 0.f;
  for (int i = t; i < PD * (ND + 8); i += 512) ((unsigned short*)sSTb[0])[i] = 0;
  PREF(0);
  CUMSUM_STAGE(0);
  er = er_n; rr = rr_n; etot = etot_n;
  PREF(1);
  barrier_lgkm();

  const int lbY = w & 3;          // Y-tile l-block for this wave
  const int pbb = (w < 4) ? 0 : 2;  // first Y-tile p-block
  const int pS = (w - 4) * 16 + cc; // S-tile p (waves 4-7)

  for (int c = 0; c < NC; ++c) {
    const int cur = c & 1, nxt = cur ^ 1;

    // ---------------- window A ----------------
    p1tile(lb1, sb1);
    if (w >= 6) p1tile(lb1, sb1 + 1);
    if (w == 4) *(uint2*)&sM[cc][16 + g * 4] = make_uint2(0u, 0u);       // tile(0,1)
    if (w == 5) *(uint2*)&sM[32 + cc][48 + g * 4] = make_uint2(0u, 0u);  // tile(2,3)

    // hoist all window-B fragments that don't depend on sM
    bf16x8 cfY = zf8;
    if (g < 2) cfY = *(const bf16x8*)&sC[lbY * 16 + cc][g * 8];
    bf16x8 stf[2], xfa[2], xfb[2];
#pragma unroll
    for (int pbi = 0; pbi < 2; ++pbi) {
      const int p_ = (pbb + pbi) * 16 + cc;
      stf[pbi] = zf8;
      if (g < 2) stf[pbi] = *(const bf16x8*)&sSTb[cur][p_][g * 8];
      xfa[pbi] = xfrag(cur, p_, g * 8);
      xfb[pbi] = zf8;
      if (lbY >= 2) xfb[pbi] = xfrag(cur, p_, 32 + g * 8);
    }
    bf16x8 ad0 = zf8, ad1 = zf8, xt0 = zf8, xt1 = zf8;
    float4 stold = make_float4(0.f, 0.f, 0.f, 0.f);
    if (w >= 4) {
      ad0 = *(const bf16x8*)&sBdT[cc][g * 8];
      ad1 = *(const bf16x8*)&sBdT[cc][32 + g * 8];
      xt0 = xfrag(cur, pS, g * 8);
      xt1 = xfrag(cur, pS, 32 + g * 8);
      stold = *(const float4*)&sSTf[cur][pS][4 * g];
    }

    barrier_lgkm();  // B2: sM ready

    // ---------------- window B ----------------
    // Y tiles (all 8 waves, 2 each)
    {
      const int lY = lbY * 16 + cc;
      bf16x8 a0 = *(const bf16x8*)&sM[lY][g * 8];
      bf16x8 a1 = zf8;
      if (lbY >= 2) a1 = *(const bf16x8*)&sM[lY][32 + g * 8];
#pragma unroll
      for (int pbi = 0; pbi < 2; ++pbi) {
        const int p_ = (pbb + pbi) * 16 + cc;
        f32x4 acc = {0.f, 0.f, 0.f, 0.f};
        acc = __builtin_amdgcn_mfma_f32_16x16x32_bf16(cfY, stf[pbi], acc, 0, 0, 0);
        acc = __builtin_amdgcn_mfma_f32_16x16x32_bf16(a0, xfa[pbi], acc, 0, 0, 0);
        if (lbY >= 2)
          acc = __builtin_amdgcn_mfma_f32_16x16x32_bf16(a1, xfb[pbi], acc, 0, 0, 0);
        const size_t yb =
            ((size_t)(b * SEQL + c * LB + lbY * 16 + 4 * g)) * NHP + h * PD + p_;
#pragma unroll
        for (int r = 0; r < 4; ++r) Yg[yb + (size_t)r * NHP] = acc[r];
      }
    }
    // S tiles (waves 4-7): ST' = ST*etot + (dec*B)^T @ X
    if (w >= 4) {
      f32x4 s4 = {0.f, 0.f, 0.f, 0.f};
      s4 = __builtin_amdgcn_mfma_f32_16x16x32_bf16(ad0, xt0, s4, 0, 0, 0);
      s4 = __builtin_amdgcn_mfma_f32_16x16x32_bf16(ad1, xt1, s4, 0, 0, 0);
      float4 nw;
      nw.x = stold.x * etot + s4[0];
      nw.y = stold.y * etot + s4[1];
      nw.z = stold.z * etot + s4[2];
      nw.w = stold.w * etot + s4[3];
      *(float4*)&sSTf[nxt][pS][4 * g] = nw;
      uint2 ub;
      ub.x = pk2(nw.x, nw.y);
      ub.y = pk2(nw.z, nw.w);
      *(uint2*)&sSTb[nxt][pS][4 * g] = ub;
    }
    // staging for chunk c+1 into alt buffers; issue prefetch for c+2
    if (c + 1 < NC) {
      CUMSUM_STAGE(nxt);
      if (c + 2 < NC) PREF(c + 2);
      er = er_n; rr = rr_n; etot = etot_n;
    }

    barrier_lgkm();  // B1 of next chunk
  }
#undef PREF
#undef CUMSUM_STAGE
}

extern "C" void kernel_launch(void* const* d_in, const int* in_sizes, int n_in,
                              void* d_out, int out_size, void* d_ws, size_t ws_size,
                              hipStream_t stream) {
  (void)in_sizes; (void)n_in; (void)out_size; (void)d_ws; (void)ws_size;
  const float* X = (const float*)d_in[0];
  const float* A = (const float*)d_in[1];
  const float* B = (const float*)d_in[2];
  const float* C = (const float*)d_in[3];
  float* Y = (float*)d_out;
  ssd_fused<<<BS * NH, 512, 0, stream>>>(X, A, B, C, Y);
}